// Round 5
// baseline (410.286 us; speedup 1.0000x reference)
//
#include <hip/hip_runtime.h>

#define NUM_EMB 1024
#define EMB_DIM 64
#define NPIX    131072                 // 32*64*64 pixels
#define ZQ_ELEMS 8388608               // NPIX * EMB_DIM

// d_out is FLOAT32: [ z_q (8388608, b-c-h-w) | loss (1) | enc (131072) ]

__global__ void vq_zero(float* __restrict__ loss_out) { loss_out[0] = 0.f; }

// numpy pairwise-sum (n=64, scalar 8-accumulator path) of x[j]*x[j].
// Caller must be in a contract(off) region so mul/add stay separate.
__device__ __forceinline__ float np_sumsq64(const float* __restrict__ x) {
    float q[EMB_DIM];
    #pragma unroll
    for (int c = 0; c < EMB_DIM; ++c) q[c] = x[c] * x[c];
    float r0 = q[0], r1 = q[1], r2 = q[2], r3 = q[3];
    float r4 = q[4], r5 = q[5], r6 = q[6], r7 = q[7];
    #pragma unroll
    for (int g = 1; g < 8; ++g) {
        r0 += q[8 * g + 0]; r1 += q[8 * g + 1];
        r2 += q[8 * g + 2]; r3 += q[8 * g + 3];
        r4 += q[8 * g + 4]; r5 += q[8 * g + 5];
        r6 += q[8 * g + 6]; r7 += q[8 * g + 7];
    }
    return ((r0 + r1) + (r2 + r3)) + ((r4 + r5) + (r6 + r7));
}

__global__ __launch_bounds__(256) void vq_nn(const float* __restrict__ z_e,
                                             const float* __restrict__ emb,
                                             float* __restrict__ zq_out,
                                             float* __restrict__ enc_out,
                                             float* __restrict__ loss_acc) {
    #pragma clang fp contract(off)
    __shared__ float s_e2[NUM_EMB];
    int tid = threadIdx.x;
    for (int k = tid; k < NUM_EMB; k += 256)
        s_e2[k] = np_sumsq64(emb + k * EMB_DIM);
    __syncthreads();

    int p  = blockIdx.x * 256 + tid;       // grid covers NPIX exactly
    int b  = p >> 12;
    int hw = p & 4095;

    const float* zp = z_e + (size_t)b * (EMB_DIM * 4096) + hw;
    float z[EMB_DIM];
    #pragma unroll
    for (int c = 0; c < EMB_DIM; ++c) z[c] = zp[(size_t)c * 4096];

    // zz exactly as np.sum(z**2, axis=-1) computes it (pairwise, n=64)
    float zz = np_sumsq64(z);

    // dist[k] = fl( fl(zz + e2[k]) - fl(2 * dot[k]) ), dot = sequential FMA
    // chain over c (BLAS sgemm microkernel accumulation order).
    // argmin with strict < over ascending k == np first-occurrence argmin.
    float b1 = 3.4e38f;
    int   i1 = 0;
    #pragma unroll 4
    for (int k = 0; k < NUM_EMB; ++k) {
        const float* ek = emb + k * EMB_DIM;   // wave-uniform address
        float acc = 0.f;
        #pragma unroll
        for (int c = 0; c < EMB_DIM; ++c) acc = fmaf(ek[c], z[c], acc);
        float sc = (zz + s_e2[k]) - 2.0f * acc;
        bool lt = sc < b1;
        b1 = lt ? sc : b1;
        i1 = lt ? k  : i1;
    }

    // Gather winning code, write z_q (f32, channel-strided) + loss partial.
    const float* eq = emb + i1 * EMB_DIM;
    float* op = zq_out + (size_t)b * (EMB_DIM * 4096) + hw;
    float ls = 0.f;
    #pragma unroll
    for (int c = 0; c < EMB_DIM; ++c) {
        float q = eq[c];
        float d = q - z[c];
        ls = fmaf(d, d, ls);
        op[(size_t)c * 4096] = q;
    }

    enc_out[p] = (float)i1;

    // wave-level reduce, one atomic per wave into the loss slot
    #pragma unroll
    for (int off = 32; off > 0; off >>= 1) ls += __shfl_down(ls, off, 64);
    if ((tid & 63) == 0) atomicAdd(loss_acc, ls);
}

__global__ void vq_final(float* __restrict__ loss_out) {
    loss_out[0] = loss_out[0] * (1.25f / (float)ZQ_ELEMS);
}

extern "C" void kernel_launch(void* const* d_in, const int* in_sizes, int n_in,
                              void* d_out, int out_size, void* d_ws, size_t ws_size,
                              hipStream_t stream) {
    const float* z_e = (const float*)d_in[0];
    const float* emb = (const float*)d_in[1];
    float* out = (float*)d_out;

    float* loss_out = out + ZQ_ELEMS;        // f32 slot 8388608
    float* enc_out  = out + ZQ_ELEMS + 1;    // f32 slots 8388609..8519680

    vq_zero<<<1, 1, 0, stream>>>(loss_out);
    vq_nn<<<NPIX / 256, 256, 0, stream>>>(z_e, emb, out, enc_out, loss_out);
    vq_final<<<1, 1, 0, stream>>>(loss_out);
}